// Round 8
// baseline (248.984 us; speedup 1.0000x reference)
//
#include <hip/hip_runtime.h>

// HMM trajectory forward, rank-1+diag rewrite, linear chunk recurrence.
// R8: two-phase.
//  Phase 1 (hmm_prep, massively parallel): resolve the divergent act gather
//    and all exps once: e1=exp(ch+start), e2=exp(ch+ombeta), eb=exp(beta)
//    -> coalesced planes in d_ws.
//  Phase 2 (hmm_fwd, time-parallel chunks): pure serial chain on coalesced
//    plane reads; P <- E1*S + E2*P, S=sum(P*EB); pow2 renorm per CH steps;
//    chunk log-contribution = log2(S_last) - log2(S_warmend) + shifts.
//  Per-(b,c) plain-store slots (no atomics, no ws memset) + tiny reduce.

#define CH   8     // register pipeline depth (double-buffered); renorm cadence
#define WARM 16    // warm-up steps (direction convergence)
#define CLEN 64    // accumulated steps per chunk
#define NB   64

template <int CTRL, int RMASK>
__device__ __forceinline__ float dpp_add(float x) {
    int yi = __builtin_amdgcn_update_dpp(
        0, __builtin_bit_cast(int, x), CTRL, RMASK, 0xf, true);
    return x + __builtin_bit_cast(float, yi);
}

// sum over 64 lanes -> wave-uniform scalar
__device__ __forceinline__ float wave_sum64(float x) {
    x = dpp_add<0x111, 0xf>(x);   // row_shr:1
    x = dpp_add<0x112, 0xf>(x);   // row_shr:2
    x = dpp_add<0x114, 0xf>(x);   // row_shr:4
    x = dpp_add<0x118, 0xf>(x);   // row_shr:8
    x = dpp_add<0x142, 0xa>(x);   // row_bcast:15 -> rows 1,3
    x = dpp_add<0x143, 0xc>(x);   // row_bcast:31 -> row 3
    return __builtin_bit_cast(float,
        __builtin_amdgcn_readlane(__builtin_bit_cast(int, x), 63));
}

// ---------- Phase 1: gather + exp planes ----------
__global__ __launch_bounds__(256)
void hmm_prep(const float* __restrict__ stop,     // (B, T+1, 64, 2)
              const float* __restrict__ start,    // (B, T+1, 64)
              const float* __restrict__ act,      // (B, T+1, 64, A)
              const int*   __restrict__ actions,  // (B, T)
              float* __restrict__ pe12,           // (B, T, 64) float2
              float* __restrict__ peb,            // (B, T, 64) float
              int T, int A, int N)
{
    const int idx = blockIdx.x * 256 + threadIdx.x;   // over B*T*64
    if (idx >= N) return;
    const int k  = idx & 63;
    const int bt = idx >> 6;              // b*T + t
    const int b  = bt / T;
    const int t  = bt - b * T;
    const size_t btk = ((size_t)b * (T + 1) + t) * NB + k;

    const int   a  = actions[bt];
    const float ch = act[btk * A + a];    // divergent gather, throughput-bound
    const float st = start[btk];
    const float2 so = *(const float2*)(stop + btk * 2);

    const size_t o = (size_t)bt * NB + k;
    ((float2*)pe12)[o] = make_float2(__expf(ch + st), __expf(ch + so.y));
    peb[o] = __expf(so.x);
}

// ---------- Phase 2: chunked serial chain ----------
__global__ __launch_bounds__(64)
void hmm_fwd(const float* __restrict__ stop,     // (B, T+1, 64, 2)
             const float2* __restrict__ pe12,    // (B, T, 64)
             const float*  __restrict__ peb,     // (B, T, 64)
             const int*    __restrict__ lengths, // (B,)
             float* __restrict__ slots,          // (B, NC)
             int T, int NC)
{
    const int bi   = blockIdx.x;
    const int c    = blockIdx.y;
    const int lane = threadIdx.x;

    const int L = lengths[bi];                          // block-uniform
    const int cstar = (L >= 2) ? ((L - 2) / CLEN) : 0;  // terminal chunk
    if (c > cstar) {
        if (lane == 0) slots[bi * NC + c] = 0.0f;
        return;
    }

    const int a     = 1 + c * CLEN;          // first accumulated step
    const int t_end = min(L, a + CLEN);      // exclusive
    const int t0    = (c == 0) ? 1 : (a - WARM);
    const int n     = t_end - t0;            // 0 possible (L==1, c==0)
    const int nwarm = a - t0;                // 0 or WARM

    const float2* q12 = pe12 + ((size_t)bi * T + t0) * NB + lane;
    const float*  qeb = peb  + ((size_t)bi * T + t0) * NB + lane;

    float p = (c == 0) ? ((lane == 0) ? 1.0f : 0.0f) : 1.0f;
    float slast   = 1.0f;   // last computed S (scale-consistent)
    float warmcap = 0.0f;   // log2 S at warm boundary (incl. shifts)
    float Eshift  = 0.0f;   // total pow2 exponent removed

    float bE1[2][CH], bE2[2][CH], bEb[2][CH];

#define LOADF(SL, j) do {                                                    \
    _Pragma("unroll")                                                        \
    for (int i = 0; i < CH; ++i) {                                           \
        const float2 v = q12[((j) * CH + i) * NB];                           \
        bE1[SL][i] = v.x;                                                    \
        bE2[SL][i] = v.y;                                                    \
        bEb[SL][i] = qeb[((j) * CH + i) * NB];                               \
    } } while (0)

#define LOADC(SL, j) do {                                                    \
    _Pragma("unroll")                                                        \
    for (int i = 0; i < CH; ++i) {                                           \
        const int tt = min(t0 + (j) * CH + i, t_end - 1);                    \
        const size_t o = ((size_t)bi * T + tt) * NB + lane;                  \
        const float2 v = pe12[o];                                            \
        bE1[SL][i] = v.x;                                                    \
        bE2[SL][i] = v.y;                                                    \
        bEb[SL][i] = peb[o];                                                 \
    } } while (0)

#define LOAD(SL, j) do {                                                     \
    if (((j) + 1) * CH <= n) LOADF(SL, j); else LOADC(SL, j); } while (0)

#define COMPUTE(SL, j) do {                                                  \
    _Pragma("unroll")                                                        \
    for (int i = 0; i < CH; ++i) {                                           \
        if ((j) * CH + i < n) {                                              \
            const float q = bE2[SL][i] * p;     /* overlaps reduction */     \
            const float s = wave_sum64(p * bEb[SL][i]);                      \
            slast = s;                                                       \
            if ((j) * CH + i == nwarm - 1)                                   \
                warmcap = __log2f(s) + Eshift;                               \
            p = fmaf(bE1[SL][i], s, q);                                      \
        }                                                                    \
    }                                                                        \
    { /* exact pow2 renorm (once per CH steps) */                            \
        const unsigned sb = __builtin_bit_cast(unsigned, slast);             \
        const int ef = (int)(sb >> 23);                                      \
        const float sc = __builtin_bit_cast(float,                           \
                             (unsigned)(254 - ef) << 23);                    \
        p *= sc;                                                             \
        slast *= sc;                                                         \
        Eshift += (float)(ef - 127);                                         \
    } } while (0)

    const int nch = (n + CH - 1) / CH;
    if (n > 0) {
        int j = 0;
        LOAD(0, 0);
        while (true) {
            if (j + 1 < nch) LOAD(1, j + 1);
            COMPUTE(0, j);
            ++j; if (j >= nch) break;
            if (j + 1 < nch) LOAD(0, j + 1);
            COMPUTE(1, j);
            ++j; if (j >= nch) break;
        }
    }

    float C2;
    if (c == cstar) {   // terminal: log2(sum_k P[k] * exp(beta_stop[L,k]))
        const float bl = stop[(((size_t)bi * (T + 1) + L) * NB + lane) * 2];
        const float s  = wave_sum64(p * __expf(bl));
        C2 = __log2f(s) + Eshift - warmcap;
    } else {
        C2 = __log2f(slast) + Eshift - warmcap;
    }

    if (lane == 0)
        slots[bi * NC + c] = C2;

#undef LOADF
#undef LOADC
#undef LOAD
#undef COMPUTE
}

__global__ __launch_bounds__(64)
void hmm_reduce(const float* __restrict__ slots, float* __restrict__ out, int M)
{
    const int lane = threadIdx.x;
    float v = 0.0f;
    for (int i = lane; i < M; i += 64) v += slots[i];
    const float s = wave_sum64(v);
    if (lane == 0)
        out[0] = -0.69314718055994531f * s;
}

extern "C" void kernel_launch(void* const* d_in, const int* in_sizes, int n_in,
                              void* d_out, int out_size, void* d_ws, size_t ws_size,
                              hipStream_t stream)
{
    const float* stop    = (const float*)d_in[0];
    const float* start   = (const float*)d_in[1];
    const float* act     = (const float*)d_in[2];
    const int*   actions = (const int*)d_in[3];
    const int*   lengths = (const int*)d_in[4];
    float* out = (float*)d_out;

    const int B   = in_sizes[4];
    const int T   = in_sizes[3] / B;
    const int Tp1 = T + 1;
    const int A   = in_sizes[2] / (B * Tp1 * 64);
    const int NC  = (T - 1 + CLEN - 1) / CLEN;   // chunks covering t=1..T-1

    float* pe12  = (float*)d_ws;                              // B*T*64 float2
    float* peb   = pe12 + (size_t)B * T * NB * 2;             // B*T*64 float
    float* slots = peb  + (size_t)B * T * NB;                 // B*NC floats

    const int N = B * T * NB;
    hmm_prep<<<dim3((N + 255) / 256), dim3(256), 0, stream>>>(
        stop, start, act, actions, pe12, peb, T, A, N);
    hmm_fwd<<<dim3(B, NC), dim3(64), 0, stream>>>(
        stop, (const float2*)pe12, peb, lengths, slots, T, NC);
    hmm_reduce<<<dim3(1), dim3(64), 0, stream>>>(slots, out, B * NC);
}